// Round 3
// baseline (335.422 us; speedup 1.0000x reference)
//
#include <hip/hip_runtime.h>

// Problem constants (B=8, H=4096, C=512, GROUPS=4)
constexpr int D         = 128;        // d = C/GROUPS
constexpr int NE        = 512;        // n_embed
constexpr int NROWS     = 131072;     // B*H*GROUPS
constexpr int CC        = 512;        // C
constexpr int OUT_ELEMS = 16777216;   // MROWS*CC

// ws layout (bytes):
//   [0]                 : float diff accumulator
//   [512]               : unsigned wave-completion counter
//   [1024, +2048)       : entab - ||e_j||^2 fp32, 512 floats
//   [4096, +262144)     : esw - 16 chunks x 16384 B:
//        [0,8192)   Eh : fp16(-2E), MFMA A-frag layout
//        [8192,16384) El: fp16((-2E - Eh)*2048)
//   [266240, +4194304)  : P[4][512][512] fp32

using half8  = __attribute__((ext_vector_type(8))) _Float16;
using f32x16 = __attribute__((ext_vector_type(16))) float;

// fp16 min normal: leading term below this is zeroed so the (possibly
// flushed-by-MFMA) denormal carries nothing; residual then holds it all.
#define F16_MINNORM 6.103515625e-05f

#define AS_STRIDE 68
#define AS_S4 17

// ---------------------------------------------------------------------------
// Kernel 0 (fused): blocks [0,256) = pgemm  P[g][j][c] = sum_k E[j,k]*W[c,g*128+k]
//                   blocks [256,272) = eprep (fp16 split of -2E + ||e||^2 table)
__launch_bounds__(256, 4)
__global__ void prep_kernel(const float* __restrict__ embed,
                            const float* __restrict__ projw,
                            unsigned short* __restrict__ esw,
                            float* __restrict__ entab,
                            float* __restrict__ ws_diff,
                            unsigned int* __restrict__ ws_cnt,
                            float* __restrict__ P) {
    __shared__ float As[64 * AS_STRIDE];
    __shared__ float Bs[64 * AS_STRIDE];
    const int tid = threadIdx.x;

    if (blockIdx.x >= 256) {
        // ---- eprep body ----
        const int chunk = blockIdx.x - 256;
        const int cl = tid >> 3;    // code in chunk (0..31) == A-row == lane&31
        const int seg = tid & 7;    // k-group of 16 (== kk)
        const float* src = embed + (size_t)(chunk * 32 + cl) * D + seg * 16;
        unsigned short* cb = esw + (size_t)chunk * 8192;  // shorts per chunk

        float ss = 0.f;
#pragma unroll
        for (int g2 = 0; g2 < 2; g2++) {   // g2 == h5 (k-half of the MFMA slice)
            float4 a = ((const float4*)src)[g2 * 2 + 0];
            float4 b = ((const float4*)src)[g2 * 2 + 1];
            float v[8] = {a.x, a.y, a.z, a.w, b.x, b.y, b.z, b.w};
            half8 t1, t2;
#pragma unroll
            for (int i = 0; i < 8; i++) {
                ss += v[i] * v[i];
                float m2 = -2.0f * v[i];
                float m2c = (__builtin_fabsf(m2) < F16_MINNORM) ? 0.0f : m2;
                _Float16 h = (_Float16)m2c;
                float r = m2 - (float)h;
                t1[i] = h;
                t2[i] = (_Float16)(r * 2048.0f);   // scaled residual, fp16-normal
            }
            const int idx = seg * 512 + g2 * 256 + cl * 8;
            *(half8*)(cb + idx) = t1;          // Eh
            *(half8*)(cb + 4096 + idx) = t2;   // El
        }
        ss += __shfl_down(ss, 4, 8);
        ss += __shfl_down(ss, 2, 8);
        ss += __shfl_down(ss, 1, 8);
        if (seg == 0) entab[chunk * 32 + cl] = ss;
        if (chunk == 0 && tid == 0) { ws_diff[0] = 0.0f; ws_cnt[0] = 0u; }
        return;
    }

    // ---- pgemm body (flattened 8x8x4 grid) ----
    const int b = blockIdx.x;
    const int cbase = (b & 7) * 64;
    const int jbase = ((b >> 3) & 7) * 64;
    const int g = b >> 6;
    const int tx = tid & 15, ty = tid >> 4;
    const int r = tid >> 2, seg = tid & 3;

    float acc[4][4];
#pragma unroll
    for (int i = 0; i < 4; i++)
#pragma unroll
        for (int j = 0; j < 4; j++) acc[i][j] = 0.f;

    for (int kb = 0; kb < D; kb += 64) {
        const float4* asrc = (const float4*)(embed + (size_t)(jbase + r) * D + kb + seg * 16);
        const float4* bsrc = (const float4*)(projw + (size_t)(cbase + r) * CC + g * D + kb + seg * 16);
        float4* adst = (float4*)&As[r * AS_STRIDE + seg * 16];
        float4* bdst = (float4*)&Bs[r * AS_STRIDE + seg * 16];
#pragma unroll
        for (int q = 0; q < 4; q++) { adst[q] = asrc[q]; bdst[q] = bsrc[q]; }
        __syncthreads();

        const float4* as4 = (const float4*)As;
        const float4* bs4 = (const float4*)Bs;
#pragma unroll 4
        for (int kk = 0; kk < 16; kk++) {
            float4 a[4], bb[4];
#pragma unroll
            for (int i = 0; i < 4; i++) a[i] = as4[(ty + 16 * i) * AS_S4 + kk];
#pragma unroll
            for (int j = 0; j < 4; j++) bb[j] = bs4[(tx + 16 * j) * AS_S4 + kk];
#pragma unroll
            for (int i = 0; i < 4; i++)
#pragma unroll
                for (int j = 0; j < 4; j++)
                    acc[i][j] += a[i].x * bb[j].x + a[i].y * bb[j].y +
                                 a[i].z * bb[j].z + a[i].w * bb[j].w;
        }
        __syncthreads();
    }
#pragma unroll
    for (int j = 0; j < 4; j++) {
#pragma unroll
        for (int i = 0; i < 4; i++)
            P[(size_t)g * 262144 + (size_t)(jbase + ty + 16 * i) * CC + cbase + tx + 16 * j] =
                acc[i][j];
    }
}

// ---------------------------------------------------------------------------
// Kernel 1: fused MFMA argmin + projection epilogue, T3/T4 pipelined staging.
// esw chunks staged into a 3-slot LDS ring via global_load_lds, issued 2 chunks
// ahead; per chunk: counted s_waitcnt vmcnt(4) (NEVER 0 in-loop) + raw
// s_barrier, so prefetch loads stay in flight across the barrier. entab lives
// in LDS so the loop's vmcnt stream contains ONLY stage loads (in-order
// retirement makes the count exact). Epilogue barrier-free (shfl indices).
__global__ __launch_bounds__(256, 3)
void argmin_fused_kernel(const float* __restrict__ z,
                         const unsigned short* __restrict__ esw,
                         const float* __restrict__ entab,
                         const float* __restrict__ P,
                         const float* __restrict__ projb,
                         float* __restrict__ ws_diff,
                         unsigned int* __restrict__ ws_cnt,
                         float* __restrict__ ind_f,
                         float* __restrict__ out,
                         float* __restrict__ diff_out) {
    __shared__ __align__(16) unsigned char ebuf[3 * 16384];   // 3-slot chunk ring
    __shared__ __align__(16) float entab_s[512];
    const int tid = threadIdx.x;
    const int lane = tid & 63;
    const int wave = tid >> 6;
    const int h5 = lane >> 5, l5 = lane & 31;
    const int rb = blockIdx.x * 128 + wave * 32;

    // stage chunk c into ring slot b (16384 B; 4096 B per wave, 4 x 1024 B)
    auto stage = [&](int c, int b) {
        const unsigned char* s = (const unsigned char*)esw + (size_t)c * 16384 +
                                 wave * 4096 + lane * 16;
        unsigned char* d = &ebuf[b * 16384 + wave * 4096];
#pragma unroll
        for (int it = 0; it < 4; it++)
            __builtin_amdgcn_global_load_lds(
                (const __attribute__((address_space(1))) unsigned int*)(s + it * 1024),
                (__attribute__((address_space(3))) unsigned int*)(d + it * 1024 + lane * 16),
                16, 0, 0);
    };

    // ---- prologue: issue entab->LDS, stage(0), stage(1); then z load+convert.
    // Issue order matters: these are oldest in the per-wave vmcnt stream.
    if (tid < 128)
        __builtin_amdgcn_global_load_lds(
            (const __attribute__((address_space(1))) unsigned int*)(entab + tid * 4),
            (__attribute__((address_space(3))) unsigned int*)(entab_s + tid * 4),
            16, 0, 0);
    stage(0, 0);
    stage(1, 1);

    // X fragments: B-frag for kk holds X[n=l5][k = kk*16 + h5*8 + j]
    half8 x1[8], x2[8];
    float xn = 0.f;
    {
        const float* zr = z + (size_t)(rb + l5) * D + h5 * 8;
#pragma unroll
        for (int kk = 0; kk < 8; kk++) {
            float4 a = *(const float4*)(zr + kk * 16);
            float4 b = *(const float4*)(zr + kk * 16 + 4);
            float v[8] = {a.x, a.y, a.z, a.w, b.x, b.y, b.z, b.w};
            half8 t1, t2;
#pragma unroll
            for (int i = 0; i < 8; i++) {
                xn += v[i] * v[i];
                float vc = (__builtin_fabsf(v[i]) < F16_MINNORM) ? 0.0f : v[i];
                _Float16 h = (_Float16)vc;
                float r = v[i] - (float)h;
                t1[i] = h;
                t2[i] = (_Float16)(r * 2048.0f);
            }
            x1[kk] = t1; x2[kk] = t2;
        }
    }

    float minv = 3.0e38f;
    int   mini = 0;

    int bs = 0;                    // ring slot of chunk c
    int ts = 2;                    // ring slot of chunk c+2
#pragma unroll 1
    for (int c = 0; c < 16; c++) {
        // chunk c's stage loads done (leave c+1's 4 in flight); all-waves align
        if (c < 15) { asm volatile("s_waitcnt vmcnt(4)" ::: "memory"); }
        else        { asm volatile("s_waitcnt vmcnt(0)" ::: "memory"); }
        __builtin_amdgcn_s_barrier();
        __builtin_amdgcn_sched_barrier(0);
        // now safe to overwrite slot ts (last read in compute(c-1), all waves past)
        if (c < 14) stage(c + 2, ts);

        const unsigned char* ldsb = &ebuf[bs * 16384];

        f32x16 accA = (f32x16)(0.0f), accB = (f32x16)(0.0f);
#pragma unroll
        for (int kk = 0; kk < 8; kk++) {
            const int fo = kk * 1024 + h5 * 512 + l5 * 16;
            half8 e1 = *(const half8*)(ldsb + fo);
            half8 e2 = *(const half8*)(ldsb + 8192 + fo);
            accA = __builtin_amdgcn_mfma_f32_32x32x16_f16(e1, x1[kk], accA, 0, 0, 0);
            accB = __builtin_amdgcn_mfma_f32_32x32x16_f16(e1, x2[kk], accB, 0, 0, 0);
            accB = __builtin_amdgcn_mfma_f32_32x32x16_f16(e2, x1[kk], accB, 0, 0, 0);
        }

        // ||e||^2 from LDS (broadcast reads, no vmcnt traffic)
        float4 enr[4];
#pragma unroll
        for (int u = 0; u < 4; u++)
            enr[u] = *(const float4*)&entab_s[c * 32 + h5 * 4 + u * 8];

        // scan: dist = accA + 2^-11 * accB + ||e||^2 ; monotone code order
        const int cb2 = c * 32 + h5 * 4;
#pragma unroll
        for (int r = 0; r < 16; r++) {
            const float en = ((const float*)&enr[r >> 2])[r & 3];
            const int cand = cb2 + (r & 3) + 8 * (r >> 2);
            float d0 = fmaf(accB[r], 4.8828125e-4f, accA[r]) + en;
            if (d0 < minv) { minv = d0; mini = cand; }  // strict < keeps first
        }
        bs = (bs == 2) ? 0 : bs + 1;
        ts = (ts == 2) ? 0 : ts + 1;
    }

    // merge the two half-wave code sets for the same x-row (col = lane&31)
    {
        float ov = __shfl_xor(minv, 32);
        int oi = __shfl_xor(mini, 32);
        if (ov < minv || (ov == minv && oi < mini)) { minv = ov; mini = oi; }
    }
    if (lane < 32) ind_f[rb + l5] = (float)mini;

    // diff partial: ||x||^2 (both k-halves) + min proxy, lanes<32 only
    float xfull = xn + __shfl_xor(xn, 32);
    float v = (lane < 32) ? (xfull + minv) : 0.0f;
#pragma unroll
    for (int off = 32; off; off >>= 1) v += __shfl_down(v, off);
    if (lane == 0) {
        atomicAdd(ws_diff, v);
        __threadfence();                          // release ws_diff before ticket
        unsigned t = atomicAdd(ws_cnt, 1u);
        if (t == 4095u) {                         // last of 4096 waves
            __threadfence();                      // acquire all ws_diff adds
            float s = atomicAdd(ws_diff, 0.0f);   // L2-coherent read
            diff_out[0] = 12.5f * s * (1.0f / 16777216.0f);
        }
    }

    // ---- fused projection epilogue (wave-local, indices via shuffle) ----
    // wave owns out-rows [ob, ob+8); out[m,c] = sum_g P[g][ind[m,g]][c] + b[c]
    const int ob = rb >> 2;
    const float4* P4  = (const float4*)P;
    const float4* pb4 = (const float4*)projb;
    float4* out4 = (float4*)out;
    const float4 bias0 = pb4[lane];
    const float4 bias1 = pb4[64 + lane];
#pragma unroll 2
    for (int r = 0; r < 8; r++) {
        const int ig0 = __shfl(mini, r * 4 + 0);
        const int ig1 = __shfl(mini, r * 4 + 1);
        const int ig2 = __shfl(mini, r * 4 + 2);
        const int ig3 = __shfl(mini, r * 4 + 3);
#pragma unroll
        for (int p = 0; p < 2; p++) {
            const int c4 = p * 64 + lane;
            float4 acc = p ? bias1 : bias0;
            float4 a0 = P4[(size_t)ig0 * 128 + c4];
            float4 a1 = P4[ 65536 + (size_t)ig1 * 128 + c4];
            float4 a2 = P4[131072 + (size_t)ig2 * 128 + c4];
            float4 a3 = P4[196608 + (size_t)ig3 * 128 + c4];
            acc.x += a0.x + a1.x + a2.x + a3.x;
            acc.y += a0.y + a1.y + a2.y + a3.y;
            acc.z += a0.z + a1.z + a2.z + a3.z;
            acc.w += a0.w + a1.w + a2.w + a3.w;
            out4[(size_t)(ob + r) * 128 + c4] = acc;
        }
    }
}

// ---------------------------------------------------------------------------
extern "C" void kernel_launch(void* const* d_in, const int* in_sizes, int n_in,
                              void* d_out, int out_size, void* d_ws, size_t ws_size,
                              hipStream_t stream) {
    const float* z     = (const float*)d_in[0];
    const float* embed = (const float*)d_in[1];
    const float* projw = (const float*)d_in[2];
    const float* projb = (const float*)d_in[3];

    float* out      = (float*)d_out;
    float* diff_out = out + OUT_ELEMS;
    float* ind_f    = out + OUT_ELEMS + 1;

    char* wsb = (char*)d_ws;
    float* ws_diff = (float*)wsb;
    unsigned int* ws_cnt = (unsigned int*)(wsb + 512);
    float* entab = (float*)(wsb + 1024);
    unsigned short* esw = (unsigned short*)(wsb + 4096);
    float* P = (float*)(wsb + 266240);

    prep_kernel<<<272, 256, 0, stream>>>(embed, projw, esw, entab, ws_diff, ws_cnt, P);
    argmin_fused_kernel<<<NROWS / 128, 256, 0, stream>>>(z, esw, entab, P, projb,
                                                         ws_diff, ws_cnt, ind_f, out,
                                                         diff_out);
}

// Round 4
// 215.955 us; speedup vs baseline: 1.5532x; 1.5532x over previous
//
#include <hip/hip_runtime.h>

// Problem constants (B=8, H=4096, C=512, GROUPS=4)
constexpr int D         = 128;        // d = C/GROUPS
constexpr int NE        = 512;        // n_embed
constexpr int NROWS     = 131072;     // B*H*GROUPS
constexpr int CC        = 512;        // C
constexpr int OUT_ELEMS = 16777216;   // MROWS*CC

// ws layout (bytes):
//   [0]                 : float diff accumulator
//   [1024, +2048)       : entab - ||e_j||^2 fp32, 512 floats
//   [4096, +262144)     : esw - 16 chunks x 16384 B:
//        [0,8192)   Eh : fp16(-2E), MFMA A-frag layout
//        [8192,16384) El: fp16((-2E - Eh)*2048)
//   [266240, +4194304)  : P[4][512][512] fp32

using half8  = __attribute__((ext_vector_type(8))) _Float16;
using f32x16 = __attribute__((ext_vector_type(16))) float;

// fp16 min normal: leading term below this is zeroed so the (possibly
// flushed-by-MFMA) denormal carries nothing; residual then holds it all.
#define F16_MINNORM 6.103515625e-05f

#define AS_STRIDE 68
#define AS_S4 17

// ---------------------------------------------------------------------------
// Kernel 0 (fused): blocks [0,256) = pgemm  P[g][j][c] = sum_k E[j,k]*W[c,g*128+k]
//                   blocks [256,272) = eprep (fp16 split of -2E + ||e||^2 table)
__launch_bounds__(256, 4)
__global__ void prep_kernel(const float* __restrict__ embed,
                            const float* __restrict__ projw,
                            unsigned short* __restrict__ esw,
                            float* __restrict__ entab,
                            float* __restrict__ ws_diff,
                            float* __restrict__ P) {
    __shared__ float As[64 * AS_STRIDE];
    __shared__ float Bs[64 * AS_STRIDE];
    const int tid = threadIdx.x;

    if (blockIdx.x >= 256) {
        // ---- eprep body ----
        const int chunk = blockIdx.x - 256;
        const int cl = tid >> 3;    // code in chunk (0..31) == A-row == lane&31
        const int seg = tid & 7;    // k-group of 16 (== kk)
        const float* src = embed + (size_t)(chunk * 32 + cl) * D + seg * 16;
        unsigned short* cb = esw + (size_t)chunk * 8192;  // shorts per chunk

        float ss = 0.f;
#pragma unroll
        for (int g2 = 0; g2 < 2; g2++) {   // g2 == h5 (k-half of the MFMA slice)
            float4 a = ((const float4*)src)[g2 * 2 + 0];
            float4 b = ((const float4*)src)[g2 * 2 + 1];
            float v[8] = {a.x, a.y, a.z, a.w, b.x, b.y, b.z, b.w};
            half8 t1, t2;
#pragma unroll
            for (int i = 0; i < 8; i++) {
                ss += v[i] * v[i];
                float m2 = -2.0f * v[i];
                float m2c = (__builtin_fabsf(m2) < F16_MINNORM) ? 0.0f : m2;
                _Float16 h = (_Float16)m2c;
                float r = m2 - (float)h;
                t1[i] = h;
                t2[i] = (_Float16)(r * 2048.0f);   // scaled residual, fp16-normal
            }
            const int idx = seg * 512 + g2 * 256 + cl * 8;
            *(half8*)(cb + idx) = t1;          // Eh
            *(half8*)(cb + 4096 + idx) = t2;   // El
        }
        ss += __shfl_down(ss, 4, 8);
        ss += __shfl_down(ss, 2, 8);
        ss += __shfl_down(ss, 1, 8);
        if (seg == 0) entab[chunk * 32 + cl] = ss;
        if (chunk == 0 && tid == 0) ws_diff[0] = 0.0f;
        return;
    }

    // ---- pgemm body (flattened 8x8x4 grid) ----
    const int b = blockIdx.x;
    const int cbase = (b & 7) * 64;
    const int jbase = ((b >> 3) & 7) * 64;
    const int g = b >> 6;
    const int tx = tid & 15, ty = tid >> 4;
    const int r = tid >> 2, seg = tid & 3;

    float acc[4][4];
#pragma unroll
    for (int i = 0; i < 4; i++)
#pragma unroll
        for (int j = 0; j < 4; j++) acc[i][j] = 0.f;

    for (int kb = 0; kb < D; kb += 64) {
        const float4* asrc = (const float4*)(embed + (size_t)(jbase + r) * D + kb + seg * 16);
        const float4* bsrc = (const float4*)(projw + (size_t)(cbase + r) * CC + g * D + kb + seg * 16);
        float4* adst = (float4*)&As[r * AS_STRIDE + seg * 16];
        float4* bdst = (float4*)&Bs[r * AS_STRIDE + seg * 16];
#pragma unroll
        for (int q = 0; q < 4; q++) { adst[q] = asrc[q]; bdst[q] = bsrc[q]; }
        __syncthreads();

        const float4* as4 = (const float4*)As;
        const float4* bs4 = (const float4*)Bs;
#pragma unroll 4
        for (int kk = 0; kk < 16; kk++) {
            float4 a[4], bb[4];
#pragma unroll
            for (int i = 0; i < 4; i++) a[i] = as4[(ty + 16 * i) * AS_S4 + kk];
#pragma unroll
            for (int j = 0; j < 4; j++) bb[j] = bs4[(tx + 16 * j) * AS_S4 + kk];
#pragma unroll
            for (int i = 0; i < 4; i++)
#pragma unroll
                for (int j = 0; j < 4; j++)
                    acc[i][j] += a[i].x * bb[j].x + a[i].y * bb[j].y +
                                 a[i].z * bb[j].z + a[i].w * bb[j].w;
        }
        __syncthreads();
    }
#pragma unroll
    for (int j = 0; j < 4; j++) {
#pragma unroll
        for (int i = 0; i < 4; i++)
            P[(size_t)g * 262144 + (size_t)(jbase + ty + 16 * i) * CC + cbase + tx + 16 * j] =
                acc[i][j];
    }
}

// ---------------------------------------------------------------------------
// Kernel 1: fused MFMA argmin + projection epilogue, T3/T4 pipelined staging.
// esw chunks staged into a 3-slot LDS ring via global_load_lds, issued 2 chunks
// ahead; per chunk: counted s_waitcnt vmcnt(4) (NEVER 0 in-loop) + raw
// s_barrier, so prefetch loads stay in flight across the barrier. entab lives
// in LDS so the loop's vmcnt stream contains ONLY stage loads (in-order
// retirement makes the count exact). NO fence/ticket in this kernel: the
// single contended, value-returning atomic per wave (+ __threadfence L2
// writeback) was rounds 1-3's ~100us regression. diff atomics are
// fire-and-forget, placed after the out-writes; finalize is its own launch.
__global__ __launch_bounds__(256, 3)
void argmin_fused_kernel(const float* __restrict__ z,
                         const unsigned short* __restrict__ esw,
                         const float* __restrict__ entab,
                         const float* __restrict__ P,
                         const float* __restrict__ projb,
                         float* __restrict__ ws_diff,
                         float* __restrict__ ind_f,
                         float* __restrict__ out) {
    __shared__ __align__(16) unsigned char ebuf[3 * 16384];   // 3-slot chunk ring
    __shared__ __align__(16) float entab_s[512];
    const int tid = threadIdx.x;
    const int lane = tid & 63;
    const int wave = tid >> 6;
    const int h5 = lane >> 5, l5 = lane & 31;
    const int rb = blockIdx.x * 128 + wave * 32;

    // stage chunk c into ring slot b (16384 B; 4096 B per wave, 4 x 1024 B)
    // LDS dst is wave-uniform base; HW adds lane*16. Global src is per-lane.
    auto stage = [&](int c, int b) {
        const unsigned char* s = (const unsigned char*)esw + (size_t)c * 16384 +
                                 wave * 4096 + lane * 16;
        unsigned char* d = &ebuf[b * 16384 + wave * 4096];
#pragma unroll
        for (int it = 0; it < 4; it++)
            __builtin_amdgcn_global_load_lds(
                (const __attribute__((address_space(1))) unsigned int*)(s + it * 1024),
                (__attribute__((address_space(3))) unsigned int*)(d + it * 1024),
                16, 0, 0);
    };

    // ---- prologue: issue entab->LDS, stage(0), stage(1); then z load+convert.
    if (tid < 128)
        __builtin_amdgcn_global_load_lds(
            (const __attribute__((address_space(1))) unsigned int*)(entab + tid * 4),
            (__attribute__((address_space(3))) unsigned int*)(entab_s + tid * 4),
            16, 0, 0);
    stage(0, 0);
    stage(1, 1);

    // X fragments: B-frag for kk holds X[n=l5][k = kk*16 + h5*8 + j]
    half8 x1[8], x2[8];
    float xn = 0.f;
    {
        const float* zr = z + (size_t)(rb + l5) * D + h5 * 8;
#pragma unroll
        for (int kk = 0; kk < 8; kk++) {
            float4 a = *(const float4*)(zr + kk * 16);
            float4 b = *(const float4*)(zr + kk * 16 + 4);
            float v[8] = {a.x, a.y, a.z, a.w, b.x, b.y, b.z, b.w};
            half8 t1, t2;
#pragma unroll
            for (int i = 0; i < 8; i++) {
                xn += v[i] * v[i];
                float vc = (__builtin_fabsf(v[i]) < F16_MINNORM) ? 0.0f : v[i];
                _Float16 h = (_Float16)vc;
                float r = v[i] - (float)h;
                t1[i] = h;
                t2[i] = (_Float16)(r * 2048.0f);
            }
            x1[kk] = t1; x2[kk] = t2;
        }
    }

    float minv = 3.0e38f;
    int   mini = 0;

    int bs = 0;                    // ring slot of chunk c
    int ts = 2;                    // ring slot of chunk c+2
#pragma unroll 1
    for (int c = 0; c < 16; c++) {
        // chunk c's stage loads done (leave c+1's 4 in flight); all-waves align
        if (c < 15) { asm volatile("s_waitcnt vmcnt(4)" ::: "memory"); }
        else        { asm volatile("s_waitcnt vmcnt(0)" ::: "memory"); }
        __builtin_amdgcn_s_barrier();
        __builtin_amdgcn_sched_barrier(0);
        // safe to overwrite slot ts (last read in compute(c-1), all waves past)
        if (c < 14) stage(c + 2, ts);

        const unsigned char* ldsb = &ebuf[bs * 16384];

        f32x16 accA = (f32x16)(0.0f), accB = (f32x16)(0.0f);
#pragma unroll
        for (int kk = 0; kk < 8; kk++) {
            const int fo = kk * 1024 + h5 * 512 + l5 * 16;
            half8 e1 = *(const half8*)(ldsb + fo);
            half8 e2 = *(const half8*)(ldsb + 8192 + fo);
            accA = __builtin_amdgcn_mfma_f32_32x32x16_f16(e1, x1[kk], accA, 0, 0, 0);
            accB = __builtin_amdgcn_mfma_f32_32x32x16_f16(e1, x2[kk], accB, 0, 0, 0);
            accB = __builtin_amdgcn_mfma_f32_32x32x16_f16(e2, x1[kk], accB, 0, 0, 0);
        }

        // ||e||^2 from LDS (broadcast reads, no vmcnt traffic)
        float4 enr[4];
#pragma unroll
        for (int u = 0; u < 4; u++)
            enr[u] = *(const float4*)&entab_s[c * 32 + h5 * 4 + u * 8];

        // scan: dist = accA + 2^-11 * accB + ||e||^2 ; monotone code order
        const int cb2 = c * 32 + h5 * 4;
#pragma unroll
        for (int r = 0; r < 16; r++) {
            const float en = ((const float*)&enr[r >> 2])[r & 3];
            const int cand = cb2 + (r & 3) + 8 * (r >> 2);
            float d0 = fmaf(accB[r], 4.8828125e-4f, accA[r]) + en;
            if (d0 < minv) { minv = d0; mini = cand; }  // strict < keeps first
        }
        bs = (bs == 2) ? 0 : bs + 1;
        ts = (ts == 2) ? 0 : ts + 1;
    }

    // merge the two half-wave code sets for the same x-row (col = lane&31)
    {
        float ov = __shfl_xor(minv, 32);
        int oi = __shfl_xor(mini, 32);
        if (ov < minv || (ov == minv && oi < mini)) { minv = ov; mini = oi; }
    }
    if (lane < 32) ind_f[rb + l5] = (float)mini;

    // ---- fused projection epilogue (wave-local, indices via shuffle) ----
    // wave owns out-rows [ob, ob+8); out[m,c] = sum_g P[g][ind[m,g]][c] + b[c]
    const int ob = rb >> 2;
    const float4* P4  = (const float4*)P;
    const float4* pb4 = (const float4*)projb;
    float4* out4 = (float4*)out;
    const float4 bias0 = pb4[lane];
    const float4 bias1 = pb4[64 + lane];
#pragma unroll 2
    for (int r = 0; r < 8; r++) {
        const int ig0 = __shfl(mini, r * 4 + 0);
        const int ig1 = __shfl(mini, r * 4 + 1);
        const int ig2 = __shfl(mini, r * 4 + 2);
        const int ig3 = __shfl(mini, r * 4 + 3);
#pragma unroll
        for (int p = 0; p < 2; p++) {
            const int c4 = p * 64 + lane;
            float4 acc = p ? bias1 : bias0;
            float4 a0 = P4[(size_t)ig0 * 128 + c4];
            float4 a1 = P4[ 65536 + (size_t)ig1 * 128 + c4];
            float4 a2 = P4[131072 + (size_t)ig2 * 128 + c4];
            float4 a3 = P4[196608 + (size_t)ig3 * 128 + c4];
            acc.x += a0.x + a1.x + a2.x + a3.x;
            acc.y += a0.y + a1.y + a2.y + a3.y;
            acc.z += a0.z + a1.z + a2.z + a3.z;
            acc.w += a0.w + a1.w + a2.w + a3.w;
            out4[(size_t)(ob + r) * 128 + c4] = acc;
        }
    }

    // diff partial: ||x||^2 (both k-halves) + min proxy, lanes<32 only.
    // Fire-and-forget (no return value -> wave does not wait), after stores.
    float xfull = xn + __shfl_xor(xn, 32);
    float v = (lane < 32) ? (xfull + minv) : 0.0f;
#pragma unroll
    for (int off = 32; off; off >>= 1) v += __shfl_down(v, off);
    if (lane == 0) atomicAdd(ws_diff, v);
}

// ---------------------------------------------------------------------------
__global__ void finalize_kernel(const float* __restrict__ ws_diff,
                                float* __restrict__ diff_out) {
    // diff = 12.5 * (sum ||x||^2 + sum min(||e||^2 - 2x.e)) / (NROWS*D)
    diff_out[0] = 12.5f * ws_diff[0] * (1.0f / 16777216.0f);
}

// ---------------------------------------------------------------------------
extern "C" void kernel_launch(void* const* d_in, const int* in_sizes, int n_in,
                              void* d_out, int out_size, void* d_ws, size_t ws_size,
                              hipStream_t stream) {
    const float* z     = (const float*)d_in[0];
    const float* embed = (const float*)d_in[1];
    const float* projw = (const float*)d_in[2];
    const float* projb = (const float*)d_in[3];

    float* out      = (float*)d_out;
    float* diff_out = out + OUT_ELEMS;
    float* ind_f    = out + OUT_ELEMS + 1;

    char* wsb = (char*)d_ws;
    float* ws_diff = (float*)wsb;
    float* entab = (float*)(wsb + 1024);
    unsigned short* esw = (unsigned short*)(wsb + 4096);
    float* P = (float*)(wsb + 266240);

    prep_kernel<<<272, 256, 0, stream>>>(embed, projw, esw, entab, ws_diff, P);
    argmin_fused_kernel<<<NROWS / 128, 256, 0, stream>>>(z, esw, entab, P, projb,
                                                         ws_diff, ind_f, out);
    finalize_kernel<<<1, 1, 0, stream>>>(ws_diff, diff_out);
}